// Round 14
// baseline (181.671 us; speedup 1.0000x reference)
//
#include <hip/hip_runtime.h>
#include <hip/hip_bf16.h>

// FullAttention: B=2, C=64, Cq=8, N=20^3=8000. Inputs CONFIRMED f32 (r2).
#define BB 2
#define CC 64
#define CQk 8
#define NN 8000
#define NBLK32 250    // 8000/32 m-blocks

using f32x4  = __attribute__((ext_vector_type(4))) float;
using bf16x8 = __attribute__((ext_vector_type(8))) short;
typedef unsigned short ushort_t;
typedef unsigned int uint_t;

__device__ __forceinline__ ushort_t f2bf(float f) {
    __hip_bfloat16 h = __float2bfloat16(f);
    return *reinterpret_cast<ushort_t*>(&h);
}

// 2^x via compiler-visible trans-op intrinsic (hazard-safe; raw asm NaN'd r5).
__device__ __forceinline__ float exp2_fast(float x) {
#if __has_builtin(__builtin_amdgcn_exp2f)
    return __builtin_amdgcn_exp2f(x);
#else
    return exp2f(x);
#endif
}

// pack two f32 -> u32 of 2 bf16 (round-half-up). Valid for finite positives.
__device__ __forceinline__ uint_t pack_bf16(float a, float b) {
    const uint_t ua = __builtin_bit_cast(uint_t, a) + 0x8000u;
    const uint_t ub = __builtin_bit_cast(uint_t, b) + 0x8000u;
    return (ua >> 16) | (ub & 0xFFFF0000u);
}

// ---------------------------------------------------------------------------
__global__ void detect_dtype(const void* __restrict__ x, int* __restrict__ flag)
{
    const float* xf = (const float*)x;
    const int t = threadIdx.x;
    const float a = fabsf(xf[t * 8]);
    const int ok = (a > 9.765625e-4f && a < 16.0f) ? 1 : 0;
    const unsigned long long m = __ballot(ok);
    if (t == 0) flag[0] = (__popcll(m) >= 48) ? 1 : 0;
}

__device__ __forceinline__ float loadF(const void* p, size_t i, int isf) {
    return isf ? ((const float*)p)[i]
               : __bfloat162float(((const __hip_bfloat16*)p)[i]);
}

// ---------------------------------------------------------------------------
// Kernel 1: QKV projection, parallelism-doubled: 500 blocks x 640 thr (10
// waves), 32-position tiles, c-dot split across lane-pairs (lane ^ 32,
// combined via __shfl_xor) -> 5000 waves (~19.5/CU, was 9.8) and half the
// per-thread serial chain. x loaded direct from global (no LDS stage).
// Fragment layouts unchanged (verified r8-r13):
//   Kfrag[b][mblk][j][lane'][8]: lane'<16 holds K[mblk*32+j*16+lane'][0..7], else 0
//   Vfrag[b][mblk][ct][lane'=hv*16+cl'][8]: elem iv = V[ct*16+cl'][mblk*32+4hv+(iv&3)+16(iv>>2)]
// ---------------------------------------------------------------------------
__global__ __launch_bounds__(640) void qkv_kernel(
    const void* __restrict__ x,
    const void* __restrict__ Wq, const void* __restrict__ bq,
    const void* __restrict__ Wk, const void* __restrict__ bk,
    const void* __restrict__ Wv, const void* __restrict__ bv,
    ushort_t* __restrict__ Qbf, ushort_t* __restrict__ Kfrag,
    ushort_t* __restrict__ Vfrag, const int* __restrict__ flag)
{
    __shared__ float sW[80][CC];     // 20.5 KB
    __shared__ float sB[80];
    __shared__ float sV[CC][33];     // 8.4 KB (+1 pad)
    __shared__ float sK[8][33];
    const int isf = flag[0];
    const int t = threadIdx.x;

    for (int i = t; i < 80 * CC; i += 640) {
        const int r = i >> 6, c = i & 63;
        float w;
        if (r < CQk)          w = loadF(Wq, (size_t)r * CC + c, isf);
        else if (r < 2 * CQk) w = loadF(Wk, (size_t)(r - CQk) * CC + c, isf);
        else                  w = loadF(Wv, (size_t)(r - 2 * CQk) * CC + c, isf);
        sW[r][c] = w;
    }
    if (t < 80) {
        float bias;
        if (t < CQk)          bias = loadF(bq, t, isf);
        else if (t < 2 * CQk) bias = loadF(bk, t - CQk, isf);
        else                  bias = loadF(bv, t - 2 * CQk, isf);
        sB[t] = bias;
    }
    __syncthreads();

    const int blk = blockIdx.x;            // 0..499 (250 per batch)
    const int b = blk / 250;
    const int n0loc = (blk % 250) * 32;    // batch-local position base
    const int nl = t & 31;                 // position within tile
    const int ch = (t >> 5) & 1;           // c-half 0/1 (lane pair via ^32)
    const int rg = t >> 6;                 // wave 0..9 -> rows rg*8..+7
    const int n = n0loc + nl;

    // x for this position, this c-half: 32 regs, direct from global
    float xv[32];
    const size_t xbase = (size_t)b * CC * NN + (size_t)(ch * 32) * NN + n;
#pragma unroll
    for (int c = 0; c < 32; ++c) xv[c] = loadF(x, xbase + (size_t)c * NN, isf);

    const int r0 = rg * 8;
    float acc[8];
#pragma unroll
    for (int rr = 0; rr < 8; ++rr) {
        const f32x4* w4 = (const f32x4*)&sW[r0 + rr][ch * 32];
        float a0 = 0.f, a1 = 0.f, a2 = 0.f, a3 = 0.f;
#pragma unroll
        for (int c4 = 0; c4 < 8; ++c4) {
            const f32x4 wv = w4[c4];
            a0 += wv.x * xv[c4 * 4 + 0];
            a1 += wv.y * xv[c4 * 4 + 1];
            a2 += wv.z * xv[c4 * 4 + 2];
            a3 += wv.w * xv[c4 * 4 + 3];
        }
        float p = (a0 + a1) + (a2 + a3);
        p += __shfl_xor(p, 32);            // combine c-halves (lane partner)
        acc[rr] = sB[r0 + rr] + p;
    }

    if (ch == 0) {
        if (rg == 0) {                     // Q rows 0..7: coalesced 16B stores
            bf16x8 pq;
#pragma unroll
            for (int j = 0; j < 8; ++j) pq[j] = (short)f2bf(acc[j] * 1.44269504089f);
            *(bf16x8*)&Qbf[((size_t)b * NN + n) * 8] = pq;
        } else if (rg == 1) {              // K rows 8..15 -> LDS
#pragma unroll
            for (int kk = 0; kk < 8; ++kk) sK[kk][nl] = acc[kk];
        } else {                           // V rows (rg-2)*8..+7 -> LDS
            const int c0v = (rg - 2) * 8;
#pragma unroll
            for (int rr = 0; rr < 8; ++rr) sV[c0v + rr][nl] = acc[rr];
        }
    }
    __syncthreads();

    // gather: coalesced 16B/lane fragment stores (1 mblk per block)
    const int mblk0 = n0loc >> 5;
    if (t < 256) {                         // V: 256 fragment words
        const int ct = t >> 6, lanep = t & 63;
        const int hp = lanep >> 4, clp = lanep & 15;
        const int c = ct * 16 + clp;
        bf16x8 pv;
#pragma unroll
        for (int iv = 0; iv < 8; ++iv) {
            const int nn = 4 * hp + (iv & 3) + ((iv >> 2) << 4);
            pv[iv] = (short)f2bf(sV[c][nn]);
        }
        *(bf16x8*)&Vfrag[(size_t)b * NN * 64
                         + ((size_t)(mblk0 * 4 + ct) * 64 + lanep) * 8] = pv;
    } else if (t < 384) {                  // K: 128 fragment words
        const int f = t - 256;
        const int j = f >> 6, lanep = f & 63;
        bf16x8 pk;
        if (lanep < 16) {
            const int nn = j * 16 + lanep;
#pragma unroll
            for (int kk = 0; kk < 8; ++kk) pk[kk] = (short)f2bf(sK[kk][nn]);
        } else {
#pragma unroll
            for (int kk = 0; kk < 8; ++kk) pk[kk] = 0;
        }
        *(bf16x8*)&Kfrag[(size_t)b * NN * 32
                         + ((size_t)(mblk0 * 2 + j) * 64 + lanep) * 8] = pk;
    }
}

// ---------------------------------------------------------------------------
// Kernel 2: MFMA flash attention PARTIALS. 256-thr (4-wave) blocks, waves =
// ms(4) m-interleave, each wave all 64 q (QT=4: 2x arithmetic intensity vs
// r13). l via VALU sum + shfl_xor (saves 16 AGPR + 4 MFMA/iter).
// grid (125, S=5, B) = 1250 blocks (~4.9/CU, reg-capped ~3-4 resident).
// __launch_bounds__(256,3): cap 170 >> need ~134 -> no spill (r10/r11 lesson).
// ---------------------------------------------------------------------------
__global__ __launch_bounds__(256, 3) void attn_partial(
    const ushort_t* __restrict__ Qbf, const ushort_t* __restrict__ Kfrag,
    const ushort_t* __restrict__ Vfrag,
    float* __restrict__ O, float* __restrict__ L, const int MSB)
{
    __shared__ float sO[64][65];
    __shared__ float sL[64];
    const int tid = threadIdx.x;
    const int lane = tid & 63;
    const int ms = tid >> 6;           // wave 0..3: m-interleave
    const int cl = lane & 15, h = lane >> 4;
    const int q0 = blockIdx.x * 64;
    const int s = blockIdx.y, b = blockIdx.z;
    const int S = gridDim.y;
    const size_t bN = (size_t)b * NN;
    const int mbase = s * MSB;         // m-blocks [mbase, mbase+MSB)

    for (int i = tid; i < 64 * 65; i += 256) (&sO[0][0])[i] = 0.f;
    if (tid < 64) sL[tid] = 0.f;
    __syncthreads();

    bf16x8 zero8;
#pragma unroll
    for (int j = 0; j < 8; ++j) zero8[j] = 0;
    bf16x8 qb[4];
#pragma unroll
    for (int t = 0; t < 4; ++t) {
        bf16x8 z = zero8;
        if (h == 0) z = *(const bf16x8*)&Qbf[(bN + q0 + t * 16 + cl) * 8];
        qb[t] = z;
    }

    const f32x4 zf = {0.f, 0.f, 0.f, 0.f};
    f32x4 acc[4][4];
    float lsum[4];
#pragma unroll
    for (int t = 0; t < 4; ++t) {
        lsum[t] = 0.f;
#pragma unroll
        for (int ct = 0; ct < 4; ++ct) acc[t][ct] = zf;
    }

    const ushort_t* Kb = Kfrag + bN * 32;
    const ushort_t* Vb = Vfrag + bN * 64;

    uint_t ko = (uint_t)(mbase + ms) * 1024 + lane * 8;
    uint_t vo = (uint_t)(mbase + ms) * 2048 + lane * 8;
    const int nit = (MSB - ms + 3) >> 2;   // MSB=50: 13,13,12,12

    for (int it = 0; it < nit; ++it) {
        bf16x8 ka0, ka1, v0, v1, v2, v3;
        ka0 = *(const bf16x8*)(Kb + ko);
        ka1 = *(const bf16x8*)(Kb + ko + 512);
        v0 = *(const bf16x8*)(Vb + vo);
        v1 = *(const bf16x8*)(Vb + vo + 512);
        v2 = *(const bf16x8*)(Vb + vo + 1024);
        v3 = *(const bf16x8*)(Vb + vo + 1536);
        ko += 4 * 1024;
        vo += 4 * 2048;

#pragma unroll
        for (int t = 0; t < 4; ++t) {
            f32x4 e0 = __builtin_amdgcn_mfma_f32_16x16x32_bf16(ka0, qb[t], zf, 0, 0, 0);
            f32x4 e1 = __builtin_amdgcn_mfma_f32_16x16x32_bf16(ka1, qb[t], zf, 0, 0, 0);
            const float x0 = exp2_fast(e0[0]), x1 = exp2_fast(e0[1]);
            const float x2 = exp2_fast(e0[2]), x3 = exp2_fast(e0[3]);
            const float x4 = exp2_fast(e1[0]), x5 = exp2_fast(e1[1]);
            const float x6 = exp2_fast(e1[2]), x7 = exp2_fast(e1[3]);
            lsum[t] += ((x0 + x1) + (x2 + x3)) + ((x4 + x5) + (x6 + x7));
            union { uint_t u[4]; bf16x8 v; } afu;
            afu.u[0] = pack_bf16(x0, x1);
            afu.u[1] = pack_bf16(x2, x3);
            afu.u[2] = pack_bf16(x4, x5);
            afu.u[3] = pack_bf16(x6, x7);
            const bf16x8 af = afu.v;
            acc[t][0] = __builtin_amdgcn_mfma_f32_16x16x32_bf16(af, v0, acc[t][0], 0, 0, 0);
            acc[t][1] = __builtin_amdgcn_mfma_f32_16x16x32_bf16(af, v1, acc[t][1], 0, 0, 0);
            acc[t][2] = __builtin_amdgcn_mfma_f32_16x16x32_bf16(af, v2, acc[t][2], 0, 0, 0);
            acc[t][3] = __builtin_amdgcn_mfma_f32_16x16x32_bf16(af, v3, acc[t][3], 0, 0, 0);
        }
    }

    // l: cross-lane reduce over h-groups (lanes h*16+cl share q=cl)
#pragma unroll
    for (int t = 0; t < 4; ++t) {
        lsum[t] += __shfl_xor(lsum[t], 16);
        lsum[t] += __shfl_xor(lsum[t], 32);
    }

    // combine 4 ms-waves in LDS
#pragma unroll
    for (int t = 0; t < 4; ++t) {
#pragma unroll
        for (int ct = 0; ct < 4; ++ct)
#pragma unroll
            for (int r = 0; r < 4; ++r)
                atomicAdd(&sO[t * 16 + 4 * h + r][ct * 16 + cl], acc[t][ct][r]);
        if (h == 0) atomicAdd(&sL[t * 16 + cl], lsum[t]);
    }
    __syncthreads();

    // write raw partials, fully coalesced
    const size_t obase = ((size_t)(b * S + s) * NN + q0) * CC;
#pragma unroll
    for (int pass = 0; pass < 16; ++pass) {
        const int idx = pass * 256 + tid;
        O[obase + idx] = sO[idx >> 6][idx & 63];
    }
    if (tid < 64) L[(size_t)(b * S + s) * NN + q0 + tid] = sL[tid];
}

// ---------------------------------------------------------------------------
// Kernel 3: combine splits, gamma * attn + x, write out (r2-proven structure).
// ---------------------------------------------------------------------------
__global__ __launch_bounds__(256) void reduce_write(
    const float* __restrict__ O, const float* __restrict__ L,
    const void* __restrict__ x, const void* __restrict__ gamma,
    void* __restrict__ out, const int S, const int* __restrict__ flag)
{
    __shared__ float sO[64][65];
    const int isf = flag[0];
    const int t = threadIdx.x;
    const int n0 = blockIdx.x * 64;
    const int b = blockIdx.y;
    const float g = loadF(gamma, 0, isf);

    {
        const int c = t & 63, nl = t >> 6;
        for (int nn = nl; nn < 64; nn += 4) {
            const int n = n0 + nn;
            float acc = 0.f, lsum = 0.f;
            for (int si = 0; si < S; ++si) {
                acc  += O[(((size_t)b * S + si) * NN + n) * CC + c];
                lsum += L[((size_t)b * S + si) * NN + n];
            }
            sO[nn][c] = g * (acc / lsum);
        }
    }
    __syncthreads();
    {
        const int nn = t & 63, cb = t >> 6;
        const int n = n0 + nn;
#pragma unroll
        for (int ci = 0; ci < 16; ++ci) {
            const int c = cb * 16 + ci;
            const size_t idx = ((size_t)b * CC + c) * NN + n;
            const float val = sO[nn][c] + loadF(x, idx, isf);
            if (isf) ((float*)out)[idx] = val;
            else     ((__hip_bfloat16*)out)[idx] = __float2bfloat16(val);
        }
    }
}

// ---------------------------------------------------------------------------
extern "C" void kernel_launch(void* const* d_in, const int* in_sizes, int n_in,
                              void* d_out, int out_size, void* d_ws, size_t ws_size,
                              hipStream_t stream)
{
    const void* x     = d_in[0];
    const void* Wq    = d_in[1];
    const void* bq    = d_in[2];
    const void* Wk    = d_in[3];
    const void* bk    = d_in[4];
    const void* Wv    = d_in[5];
    const void* bv    = d_in[6];
    const void* gamma = d_in[7];

    char* base = (char*)d_ws;
    int* flag = (int*)base;
    size_t off = 256;
    ushort_t* Qbf   = (ushort_t*)(base + off); off += (size_t)BB * NN * CQk * 2;
    ushort_t* Kfrag = (ushort_t*)(base + off); off += (size_t)BB * NN * 32 * 2;
    ushort_t* Vfrag = (ushort_t*)(base + off); off += (size_t)BB * NN * 64 * 2;
    off = (off + 255) & ~(size_t)255;

    // m-split: prefer S=5 (1250 blocks); degrade 5 -> 2 -> 1 if ws is tight.
    int S = 5;
    while (S > 1 && off + (size_t)BB * S * NN * (CC + 1) * 4 > ws_size)
        S = (S == 5) ? 2 : 1;
    const int MSB = NBLK32 / S;            // 50 / 125 / 250
    float* Obuf = (float*)(base + off);
    float* Lbuf = Obuf + (size_t)BB * S * NN * CC;

    detect_dtype<<<1, 64, 0, stream>>>(x, flag);

    qkv_kernel<<<dim3(500), 640, 0, stream>>>(x, Wq, bq, Wk, bk, Wv, bv,
                                              Qbf, Kfrag, Vfrag, flag);

    dim3 g2(NN / 64, S, BB);
    attn_partial<<<g2, 256, 0, stream>>>(Qbf, Kfrag, Vfrag, Obuf, Lbuf, MSB);

    dim3 g3(NN / 64, BB);
    reduce_write<<<g3, 256, 0, stream>>>(Obuf, Lbuf, x, gamma, d_out, S, flag);
}

// Round 15
// 150.396 us; speedup vs baseline: 1.2079x; 1.2079x over previous
//
#include <hip/hip_runtime.h>
#include <hip/hip_bf16.h>

// FullAttention: B=2, C=64, Cq=8, N=20^3=8000. Inputs CONFIRMED f32 (r2).
#define BB 2
#define CC 64
#define CQk 8
#define NN 8000
#define NBLK32 250    // 8000/32 m-blocks

using f32x4  = __attribute__((ext_vector_type(4))) float;
using bf16x8 = __attribute__((ext_vector_type(8))) short;
typedef unsigned short ushort_t;
typedef unsigned int uint_t;

__device__ __forceinline__ ushort_t f2bf(float f) {
    __hip_bfloat16 h = __float2bfloat16(f);
    return *reinterpret_cast<ushort_t*>(&h);
}

// 2^x via compiler-visible trans-op intrinsic (hazard-safe; raw asm NaN'd r5).
__device__ __forceinline__ float exp2_fast(float x) {
#if __has_builtin(__builtin_amdgcn_exp2f)
    return __builtin_amdgcn_exp2f(x);
#else
    return exp2f(x);
#endif
}

// pack two f32 -> u32 of 2 bf16 (round-half-up). Valid for finite positives.
__device__ __forceinline__ uint_t pack_bf16(float a, float b) {
    const uint_t ua = __builtin_bit_cast(uint_t, a) + 0x8000u;
    const uint_t ub = __builtin_bit_cast(uint_t, b) + 0x8000u;
    return (ua >> 16) | (ub & 0xFFFF0000u);
}

// ---------------------------------------------------------------------------
__global__ void detect_dtype(const void* __restrict__ x, int* __restrict__ flag)
{
    const float* xf = (const float*)x;
    const int t = threadIdx.x;
    const float a = fabsf(xf[t * 8]);
    const int ok = (a > 9.765625e-4f && a < 16.0f) ? 1 : 0;
    const unsigned long long m = __ballot(ok);
    if (t == 0) flag[0] = (__popcll(m) >= 48) ? 1 : 0;
}

__device__ __forceinline__ float loadF(const void* p, size_t i, int isf) {
    return isf ? ((const float*)p)[i]
               : __bfloat162float(((const __hip_bfloat16*)p)[i]);
}

// ---------------------------------------------------------------------------
// Kernel 1: QKV projection (r14 version, verified). 500 blocks x 640 thr,
// 32-position tiles, c-dot split across lane-pairs (^32), fragment-major
// coalesced stores.
//   Kfrag[b][mblk][j][lane'][8]: lane'<16 holds K[mblk*32+j*16+lane'][0..7], else 0
//   Vfrag[b][mblk][ct][lane'=hv*16+cl'][8]: elem iv = V[ct*16+cl'][mblk*32+4hv+(iv&3)+16(iv>>2)]
// ---------------------------------------------------------------------------
__global__ __launch_bounds__(640) void qkv_kernel(
    const void* __restrict__ x,
    const void* __restrict__ Wq, const void* __restrict__ bq,
    const void* __restrict__ Wk, const void* __restrict__ bk,
    const void* __restrict__ Wv, const void* __restrict__ bv,
    ushort_t* __restrict__ Qbf, ushort_t* __restrict__ Kfrag,
    ushort_t* __restrict__ Vfrag, const int* __restrict__ flag)
{
    __shared__ float sW[80][CC];     // 20.5 KB
    __shared__ float sB[80];
    __shared__ float sV[CC][33];     // 8.4 KB (+1 pad)
    __shared__ float sK[8][33];
    const int isf = flag[0];
    const int t = threadIdx.x;

    for (int i = t; i < 80 * CC; i += 640) {
        const int r = i >> 6, c = i & 63;
        float w;
        if (r < CQk)          w = loadF(Wq, (size_t)r * CC + c, isf);
        else if (r < 2 * CQk) w = loadF(Wk, (size_t)(r - CQk) * CC + c, isf);
        else                  w = loadF(Wv, (size_t)(r - 2 * CQk) * CC + c, isf);
        sW[r][c] = w;
    }
    if (t < 80) {
        float bias;
        if (t < CQk)          bias = loadF(bq, t, isf);
        else if (t < 2 * CQk) bias = loadF(bk, t - CQk, isf);
        else                  bias = loadF(bv, t - 2 * CQk, isf);
        sB[t] = bias;
    }
    __syncthreads();

    const int blk = blockIdx.x;            // 0..499 (250 per batch)
    const int b = blk / 250;
    const int n0loc = (blk % 250) * 32;    // batch-local position base
    const int nl = t & 31;
    const int ch = (t >> 5) & 1;           // c-half (lane pair via ^32)
    const int rg = t >> 6;                 // wave 0..9 -> rows rg*8..+7
    const int n = n0loc + nl;

    float xv[32];
    const size_t xbase = (size_t)b * CC * NN + (size_t)(ch * 32) * NN + n;
#pragma unroll
    for (int c = 0; c < 32; ++c) xv[c] = loadF(x, xbase + (size_t)c * NN, isf);

    const int r0 = rg * 8;
    float acc[8];
#pragma unroll
    for (int rr = 0; rr < 8; ++rr) {
        const f32x4* w4 = (const f32x4*)&sW[r0 + rr][ch * 32];
        float a0 = 0.f, a1 = 0.f, a2 = 0.f, a3 = 0.f;
#pragma unroll
        for (int c4 = 0; c4 < 8; ++c4) {
            const f32x4 wv = w4[c4];
            a0 += wv.x * xv[c4 * 4 + 0];
            a1 += wv.y * xv[c4 * 4 + 1];
            a2 += wv.z * xv[c4 * 4 + 2];
            a3 += wv.w * xv[c4 * 4 + 3];
        }
        float p = (a0 + a1) + (a2 + a3);
        p += __shfl_xor(p, 32);
        acc[rr] = sB[r0 + rr] + p;
    }

    if (ch == 0) {
        if (rg == 0) {
            bf16x8 pq;
#pragma unroll
            for (int j = 0; j < 8; ++j) pq[j] = (short)f2bf(acc[j] * 1.44269504089f);
            *(bf16x8*)&Qbf[((size_t)b * NN + n) * 8] = pq;
        } else if (rg == 1) {
#pragma unroll
            for (int kk = 0; kk < 8; ++kk) sK[kk][nl] = acc[kk];
        } else {
            const int c0v = (rg - 2) * 8;
#pragma unroll
            for (int rr = 0; rr < 8; ++rr) sV[c0v + rr][nl] = acc[rr];
        }
    }
    __syncthreads();

    const int mblk0 = n0loc >> 5;
    if (t < 256) {                         // V: 256 fragment words
        const int ct = t >> 6, lanep = t & 63;
        const int hp = lanep >> 4, clp = lanep & 15;
        const int c = ct * 16 + clp;
        bf16x8 pv;
#pragma unroll
        for (int iv = 0; iv < 8; ++iv) {
            const int nn = 4 * hp + (iv & 3) + ((iv >> 2) << 4);
            pv[iv] = (short)f2bf(sV[c][nn]);
        }
        *(bf16x8*)&Vfrag[(size_t)b * NN * 64
                         + ((size_t)(mblk0 * 4 + ct) * 64 + lanep) * 8] = pv;
    } else if (t < 384) {                  // K: 128 fragment words
        const int f = t - 256;
        const int j = f >> 6, lanep = f & 63;
        bf16x8 pk;
        if (lanep < 16) {
            const int nn = j * 16 + lanep;
#pragma unroll
            for (int kk = 0; kk < 8; ++kk) pk[kk] = (short)f2bf(sK[kk][nn]);
        } else {
#pragma unroll
            for (int kk = 0; kk < 8; ++kk) pk[kk] = 0;
        }
        *(bf16x8*)&Kfrag[(size_t)b * NN * 32
                         + ((size_t)(mblk0 * 2 + j) * 64 + lanep) * 8] = pk;
    }
}

// ---------------------------------------------------------------------------
// Kernel 2: LDS-staged MFMA flash attention PARTIALS.
// Block = 512 thr (8 waves) = qh(4 q-tiles of 16) x mh(2 mblks of the chunk).
// Chunk = 2 mblks (12KB: K 2x2KB + V 2x4KB), double-buffered in LDS; staged
// by all 8 waves (12 coalesced 1KB wave-loads), shared by all -> per-wave
// global loads cut 8x and registers ~75 (QT=1, acc 16 AGPR) -> ~6 waves/SIMD;
// LDS 41KB -> 3 blocks/CU -> ~24 waves/CU. ds_reads are base+lane*16B:
// conflict-free. Early-issued stage loads pinned by sched_barrier(0) (T14).
// grid (125, S=5, B); MSB=50 -> 25 chunks, no tail. NO min-waves bound
// (r10/r11 lesson: never cap regs below need).
// ---------------------------------------------------------------------------
__global__ __launch_bounds__(512) void attn_partial(
    const ushort_t* __restrict__ Qbf, const ushort_t* __restrict__ Kfrag,
    const ushort_t* __restrict__ Vfrag,
    float* __restrict__ O, float* __restrict__ L, const int MSB)
{
    __shared__ __align__(16) ushort_t sbuf[2][6144];  // 2 x 12KB chunk
    __shared__ float sO[64][65];
    __shared__ float sL[64];

    const int tid = threadIdx.x;
    const int lane = tid & 63;
    const int w = tid >> 6;            // wave 0..7
    const int qh = w & 3;              // q-tile (16 rows)
    const int mh = w >> 2;             // mblk within chunk (0/1)
    const int cl = lane & 15, h = lane >> 4;
    const int q0 = blockIdx.x * 64;
    const int s = blockIdx.y, b = blockIdx.z;
    const int S = gridDim.y;
    const size_t bN = (size_t)b * NN;
    const int mbase = s * MSB;

    for (int i = tid; i < 64 * 65; i += 512) (&sO[0][0])[i] = 0.f;
    if (tid < 64) sL[tid] = 0.f;

    bf16x8 zero8;
#pragma unroll
    for (int j = 0; j < 8; ++j) zero8[j] = 0;
    bf16x8 qb = zero8;
    if (h == 0) qb = *(const bf16x8*)&Qbf[(bN + q0 + qh * 16 + cl) * 8];

    const f32x4 zf = {0.f, 0.f, 0.f, 0.f};
    f32x4 acc[4];
#pragma unroll
    for (int ct = 0; ct < 4; ++ct) acc[ct] = zf;
    float lsum = 0.f;

    const ushort_t* Kb = Kfrag + bN * 32;
    const ushort_t* Vb = Vfrag + bN * 64;

    // stage-load assignment: 12 x 1KB wave-loads per chunk
    const int li0 = w;                 // 0..3 -> K, 4..7 -> V low
    const int li1 = 8 + w;             // w<4 only -> V high
    const int d0 = (li0 < 4) ? li0 * 512 + lane * 8
                             : 2048 + (li0 - 4) * 512 + lane * 8;
    const int d1 = 2048 + (li1 - 4) * 512 + lane * 8;
    const int nchunk = MSB >> 1;       // MSB even by construction (50 or 250)

    // prologue: stage chunk 0 into buf0
    {
        const size_t M = (size_t)mbase;
        const ushort_t* p0 = (li0 < 4) ? Kb + M * 1024 + li0 * 512 + lane * 8
                                       : Vb + M * 2048 + (li0 - 4) * 512 + lane * 8;
        *(bf16x8*)&sbuf[0][d0] = *(const bf16x8*)p0;
        if (w < 4)
            *(bf16x8*)&sbuf[0][d1] =
                *(const bf16x8*)(Vb + M * 2048 + (li1 - 4) * 512 + lane * 8);
    }
    __syncthreads();

    for (int c = 0; c < nchunk; ++c) {
        const int cur = c & 1;
        const bool have = (c + 1 < nchunk);
        // issue next-chunk loads EARLY (clamped index when no next chunk)
        const size_t Mn = (size_t)(mbase + (have ? (c + 1) : c) * 2);
        const ushort_t* p0 = (li0 < 4) ? Kb + Mn * 1024 + li0 * 512 + lane * 8
                                       : Vb + Mn * 2048 + (li0 - 4) * 512 + lane * 8;
        const bf16x8 s0 = *(const bf16x8*)p0;
        bf16x8 s1 = zero8;
        if (w < 4)
            s1 = *(const bf16x8*)(Vb + Mn * 2048 + (li1 - 4) * 512 + lane * 8);
        __builtin_amdgcn_sched_barrier(0);   // pin loads above compute

        // compute this wave's (qh, mh) on sbuf[cur]
        const ushort_t* sb = &sbuf[cur][0];
        const bf16x8 ka0 = *(const bf16x8*)&sb[mh * 1024 + lane * 8];
        const bf16x8 ka1 = *(const bf16x8*)&sb[mh * 1024 + 512 + lane * 8];
        const bf16x8 v0  = *(const bf16x8*)&sb[2048 + mh * 2048 + lane * 8];
        const bf16x8 v1  = *(const bf16x8*)&sb[2048 + mh * 2048 + 512 + lane * 8];
        const bf16x8 v2  = *(const bf16x8*)&sb[2048 + mh * 2048 + 1024 + lane * 8];
        const bf16x8 v3  = *(const bf16x8*)&sb[2048 + mh * 2048 + 1536 + lane * 8];

        const f32x4 e0 = __builtin_amdgcn_mfma_f32_16x16x32_bf16(ka0, qb, zf, 0, 0, 0);
        const f32x4 e1 = __builtin_amdgcn_mfma_f32_16x16x32_bf16(ka1, qb, zf, 0, 0, 0);
        const float x0 = exp2_fast(e0[0]), x1 = exp2_fast(e0[1]);
        const float x2 = exp2_fast(e0[2]), x3 = exp2_fast(e0[3]);
        const float x4 = exp2_fast(e1[0]), x5 = exp2_fast(e1[1]);
        const float x6 = exp2_fast(e1[2]), x7 = exp2_fast(e1[3]);
        lsum += ((x0 + x1) + (x2 + x3)) + ((x4 + x5) + (x6 + x7));
        union { uint_t u[4]; bf16x8 v; } afu;
        afu.u[0] = pack_bf16(x0, x1);
        afu.u[1] = pack_bf16(x2, x3);
        afu.u[2] = pack_bf16(x4, x5);
        afu.u[3] = pack_bf16(x6, x7);
        const bf16x8 af = afu.v;
        acc[0] = __builtin_amdgcn_mfma_f32_16x16x32_bf16(af, v0, acc[0], 0, 0, 0);
        acc[1] = __builtin_amdgcn_mfma_f32_16x16x32_bf16(af, v1, acc[1], 0, 0, 0);
        acc[2] = __builtin_amdgcn_mfma_f32_16x16x32_bf16(af, v2, acc[2], 0, 0, 0);
        acc[3] = __builtin_amdgcn_mfma_f32_16x16x32_bf16(af, v3, acc[3], 0, 0, 0);

        __syncthreads();                 // all waves done reading sbuf[cur]
        if (have) {
            *(bf16x8*)&sbuf[cur ^ 1][d0] = s0;
            if (w < 4) *(bf16x8*)&sbuf[cur ^ 1][d1] = s1;
        }
        __syncthreads();                 // next chunk visible
    }

    // l: reduce over h-groups (lanes h*16+cl share q = cl)
    lsum += __shfl_xor(lsum, 16);
    lsum += __shfl_xor(lsum, 32);

    // combine: 2 mh-waves per qh (2-way contention)
#pragma unroll
    for (int ct = 0; ct < 4; ++ct)
#pragma unroll
        for (int r = 0; r < 4; ++r)
            atomicAdd(&sO[qh * 16 + 4 * h + r][ct * 16 + cl], acc[ct][r]);
    if (h == 0) atomicAdd(&sL[qh * 16 + cl], lsum);
    __syncthreads();

    // write raw partials, fully coalesced
    const size_t obase = ((size_t)(b * S + s) * NN + q0) * CC;
#pragma unroll
    for (int pass = 0; pass < 8; ++pass) {
        const int idx = pass * 512 + tid;
        O[obase + idx] = sO[idx >> 6][idx & 63];
    }
    if (tid < 64) L[(size_t)(b * S + s) * NN + q0 + tid] = sL[tid];
}

// ---------------------------------------------------------------------------
// Kernel 3: combine splits, gamma * attn + x, write out (r2-proven structure).
// ---------------------------------------------------------------------------
__global__ __launch_bounds__(256) void reduce_write(
    const float* __restrict__ O, const float* __restrict__ L,
    const void* __restrict__ x, const void* __restrict__ gamma,
    void* __restrict__ out, const int S, const int* __restrict__ flag)
{
    __shared__ float sO[64][65];
    const int isf = flag[0];
    const int t = threadIdx.x;
    const int n0 = blockIdx.x * 64;
    const int b = blockIdx.y;
    const float g = loadF(gamma, 0, isf);

    {
        const int c = t & 63, nl = t >> 6;
        for (int nn = nl; nn < 64; nn += 4) {
            const int n = n0 + nn;
            float acc = 0.f, lsum = 0.f;
            for (int si = 0; si < S; ++si) {
                acc  += O[(((size_t)b * S + si) * NN + n) * CC + c];
                lsum += L[((size_t)b * S + si) * NN + n];
            }
            sO[nn][c] = g * (acc / lsum);
        }
    }
    __syncthreads();
    {
        const int nn = t & 63, cb = t >> 6;
        const int n = n0 + nn;
#pragma unroll
        for (int ci = 0; ci < 16; ++ci) {
            const int c = cb * 16 + ci;
            const size_t idx = ((size_t)b * CC + c) * NN + n;
            const float val = sO[nn][c] + loadF(x, idx, isf);
            if (isf) ((float*)out)[idx] = val;
            else     ((__hip_bfloat16*)out)[idx] = __float2bfloat16(val);
        }
    }
}

// ---------------------------------------------------------------------------
extern "C" void kernel_launch(void* const* d_in, const int* in_sizes, int n_in,
                              void* d_out, int out_size, void* d_ws, size_t ws_size,
                              hipStream_t stream)
{
    const void* x     = d_in[0];
    const void* Wq    = d_in[1];
    const void* bq    = d_in[2];
    const void* Wk    = d_in[3];
    const void* bk    = d_in[4];
    const void* Wv    = d_in[5];
    const void* bv    = d_in[6];
    const void* gamma = d_in[7];

    char* base = (char*)d_ws;
    int* flag = (int*)base;
    size_t off = 256;
    ushort_t* Qbf   = (ushort_t*)(base + off); off += (size_t)BB * NN * CQk * 2;
    ushort_t* Kfrag = (ushort_t*)(base + off); off += (size_t)BB * NN * 32 * 2;
    ushort_t* Vfrag = (ushort_t*)(base + off); off += (size_t)BB * NN * 64 * 2;
    off = (off + 255) & ~(size_t)255;

    // m-split: S=5 (MSB=50, even chunks). Fallback S=1 (MSB=250, even) — S=2
    // would give odd chunk count (125) and break the 2-mblk chunking.
    int S = 5;
    if (off + (size_t)BB * S * NN * (CC + 1) * 4 > ws_size) S = 1;
    const int MSB = NBLK32 / S;
    float* Obuf = (float*)(base + off);
    float* Lbuf = Obuf + (size_t)BB * S * NN * CC;

    detect_dtype<<<1, 64, 0, stream>>>(x, flag);

    qkv_kernel<<<dim3(500), 640, 0, stream>>>(x, Wq, bq, Wk, bk, Wv, bv,
                                              Qbf, Kfrag, Vfrag, flag);

    dim3 g2(NN / 64, S, BB);
    attn_partial<<<g2, 512, 0, stream>>>(Qbf, Kfrag, Vfrag, Obuf, Lbuf, MSB);

    dim3 g3(NN / 64, BB);
    reduce_write<<<g3, 256, 0, stream>>>(Obuf, Lbuf, x, gamma, d_out, S, flag);
}